// Round 17
// baseline (196.390 us; speedup 1.0000x reference)
//
#include <hip/hip_runtime.h>

#define N_NODES 100000
#define N_PAD 100032                   // 64-aligned node count for gemm tiles
#define N_EDGES 1600000
#define HID 150
#define KPAD 160
#define HROW 168                       // shorts per H row (336 B, 16B-aligned, 2-way-bank stride)
#define OUTF 64
#define BSH 9
#define BUKN 512
#define NBUK ((N_NODES + BUKN - 1) / BUKN)   // 196 buckets
#define CAP 10240
#define TILE 4096
#define NTILE ((N_EDGES + TILE - 1) / TILE)  // 391 tiles

typedef short bf16x8 __attribute__((ext_vector_type(8)));
typedef float f32x4 __attribute__((ext_vector_type(4)));

__device__ __forceinline__ unsigned short f2bf(float f) {
    union { float f; unsigned u; } v; v.f = f;
    unsigned r = (v.u + 0x7FFFu + ((v.u >> 16) & 1u)) >> 16;
    return (unsigned short)r;
}

__device__ __forceinline__ float bf2f(unsigned short b) {
    union { unsigned u; float f; } v;
    v.u = ((unsigned)b) << 16;
    return v.f;
}

// ---------------- init (1 block): zero bukcnt, pack W1t + W2T ----------------
__global__ __launch_bounds__(256) void k_init(const float* __restrict__ W1s,
                                              const float* __restrict__ W1n,
                                              const float* __restrict__ b1,
                                              const float* __restrict__ W2s,
                                              const float* __restrict__ W2n,
                                              float* __restrict__ W1t,
                                              unsigned short* __restrict__ W2T,
                                              int* __restrict__ bukcnt) {
    int tid = threadIdx.x;
    if (tid < NBUK) bukcnt[tid] = 0;
    for (int k = tid; k < KPAD; k += 256) {
        bool ok = (k < HID);
        W1t[k * 8 + 0] = ok ? W1s[0 * HID + k] : 0.0f;
        W1t[k * 8 + 1] = ok ? W1s[1 * HID + k] : 0.0f;
        W1t[k * 8 + 2] = ok ? W1s[2 * HID + k] : 0.0f;
        W1t[k * 8 + 3] = ok ? b1[k] : 0.0f;
        W1t[k * 8 + 4] = ok ? W1n[0 * HID + k] : 0.0f;
        W1t[k * 8 + 5] = ok ? W1n[1 * HID + k] : 0.0f;
        W1t[k * 8 + 6] = ok ? W1n[2 * HID + k] : 0.0f;
        W1t[k * 8 + 7] = 0.0f;
    }
    for (int idx = tid; idx < 128 * KPAD; idx += 256) {
        int c = idx / KPAD, k = idx - c * KPAD;
        float v = 0.0f;
        if (k < HID) v = (c < 64) ? W2s[k * 64 + c] : W2n[k * 64 + (c - 64)];
        W2T[idx] = f2bf(v);
    }
}

// ---------------- partition: x4 pad + bin edges into per-bucket arenas ----------------
__global__ __launch_bounds__(256) void k_part(const float* __restrict__ x,
                                              float4* __restrict__ x4,
                                              const int* __restrict__ src,
                                              const int* __restrict__ dst,
                                              int* __restrict__ bukcnt,
                                              unsigned int* __restrict__ pairbuf) {
    __shared__ int cnt[NBUK];
    __shared__ int gbase[NBUK];
    int tid = threadIdx.x;
    int idx = blockIdx.x * 256 + tid;
    if (idx < N_NODES)
        x4[idx] = make_float4(x[idx * 3 + 0], x[idx * 3 + 1], x[idx * 3 + 2], 0.0f);

    int e0 = blockIdx.x * TILE;
    int n = min(TILE, N_EDGES - e0);

    for (int i = tid; i < NBUK; i += 256) cnt[i] = 0;
    __syncthreads();

    int myb[16];
    int mypos[16];
    unsigned int myv[16];
    #pragma unroll
    for (int j = 0; j < 16; ++j) {
        int ei = tid + j * 256;
        myb[j] = -1;
        if (ei < n) {
            int s = src[e0 + ei];
            int d = dst[e0 + ei];
            int b = d >> BSH;
            myb[j] = b;
            myv[j] = ((unsigned int)(d & (BUKN - 1)) << 17) | (unsigned int)s;
            mypos[j] = atomicAdd(&cnt[b], 1);
        }
    }
    __syncthreads();

    if (tid < NBUK) {
        int c = cnt[tid];
        gbase[tid] = c ? (tid * CAP + atomicAdd(&bukcnt[tid], c)) : 0;
    }
    __syncthreads();

    #pragma unroll
    for (int j = 0; j < 16; ++j) {
        if (myb[j] >= 0)
            pairbuf[gbase[myb[j]] + mypos[j]] = myv[j];
    }
}

// ---------------- per-bucket CSR finish: hist + scan + rows/invd + scatter ----------
__global__ __launch_bounds__(512) void k_fine(const int* __restrict__ bukcnt,
                                              const unsigned int* __restrict__ pairbuf,
                                              int2* __restrict__ rows,
                                              float* __restrict__ invd,
                                              int* __restrict__ csr_src) {
    __shared__ int deg[BUKN];
    __shared__ int sc[BUKN];
    int tid = threadIdx.x;
    int b = blockIdx.x;
    int n0 = b << BSH;
    int lo = b * CAP;
    int hi = lo + bukcnt[b];

    deg[tid] = 0;
    __syncthreads();
    for (int i = lo + tid; i < hi; i += 512)
        atomicAdd(&deg[pairbuf[i] >> 17], 1);
    __syncthreads();

    int d = deg[tid];
    sc[tid] = d;
    __syncthreads();
    for (int o = 1; o < 512; o <<= 1) {
        int a = sc[tid];
        int ap = (tid >= o) ? sc[tid - o] : 0;
        __syncthreads();
        sc[tid] = a + ap;
        __syncthreads();
    }
    int r = lo + sc[tid] - d;
    int node = n0 + tid;
    if (node < N_NODES) {
        rows[node] = make_int2(r, r + d);
        invd[node] = 1.0f / fmaxf((float)d, 1.0f);
    }
    __syncthreads();
    deg[tid] = r;
    __syncthreads();
    for (int i = lo + tid; i < hi; i += 512) {
        unsigned int v = pairbuf[i];
        int dl = v >> 17;
        int ofs = atomicAdd(&deg[dl], 1);
        csr_src[ofs] = (int)(v & 0x1FFFF);
    }
}

// ---------------- layer-1: neighbor mean + h materialization -> H[n][168] bf16 --------
// 4 lanes per node. After the butterfly, ALL 4 lanes hold the full sums; lane sub
// computes h for j = sub + 4m (m=0..4): k = 8j..8j+7, one 16B store each.
__global__ __launch_bounds__(256) void k_agg1h(const int2* __restrict__ rows,
                                               const int* __restrict__ csr_src,
                                               const float4* __restrict__ x4,
                                               const float* __restrict__ invd,
                                               const float* __restrict__ W1t,
                                               unsigned short* __restrict__ H) {
    int wid = (blockIdx.x * blockDim.x + threadIdx.x) >> 6;
    int lane = threadIdx.x & 63;
    int n = wid * 16 + (lane >> 2);
    if (n >= N_NODES) return;
    int sub = lane & 3;
    int2 re = rows[n];
    float s0 = 0.f, s1 = 0.f, s2 = 0.f;
    for (int i = re.x + sub; i < re.y; i += 4) {
        float4 v = x4[csr_src[i]];
        s0 += v.x; s1 += v.y; s2 += v.z;
    }
    s0 += __shfl_xor(s0, 1, 64); s0 += __shfl_xor(s0, 2, 64);
    s1 += __shfl_xor(s1, 1, 64); s1 += __shfl_xor(s1, 2, 64);
    s2 += __shfl_xor(s2, 1, 64); s2 += __shfl_xor(s2, 2, 64);
    float id = invd[n];
    float xn0 = s0 * id, xn1 = s1 * id, xn2 = s2 * id;
    float4 xs = x4[n];

    #pragma unroll
    for (int m = 0; m < 5; ++m) {
        int j = sub + 4 * m;          // 0..19 over the 4 lanes
        int k = j * 8;
        unsigned int pk[4];
        #pragma unroll
        for (int jj = 0; jj < 4; ++jj) {
            int k2 = k + 2 * jj;
            float4 wa0 = *(const float4*)&W1t[k2 * 8 + 0];
            float4 wb0 = *(const float4*)&W1t[k2 * 8 + 4];
            float4 wa1 = *(const float4*)&W1t[k2 * 8 + 8];
            float4 wb1 = *(const float4*)&W1t[k2 * 8 + 12];
            float h0 = wa0.w + xs.x * wa0.x + xs.y * wa0.y + xs.z * wa0.z
                             + xn0 * wb0.x + xn1 * wb0.y + xn2 * wb0.z;
            float h1 = wa1.w + xs.x * wa1.x + xs.y * wa1.y + xs.z * wa1.z
                             + xn0 * wb1.x + xn1 * wb1.y + xn2 * wb1.z;
            h0 = fmaxf(h0, 0.0f);
            h1 = fmaxf(h1, 0.0f);
            pk[jj] = (unsigned int)f2bf(h0) | ((unsigned int)f2bf(h1) << 16);
        }
        uint4 v = make_uint4(pk[0], pk[1], pk[2], pk[3]);
        *(uint4*)&H[(size_t)n * HROW + k] = v;    // byte offset n*336 + j*16, aligned
    }
}

// ---------------- layer-2 GEMM: H staged via global_load_lds, MFMA ----------------
// 64-node tile, 4 waves. A-tile = 21504 contiguous bytes of H -> LDS (21 x 1024B
// async issues). Then ds_read_b128 A-frags (stride 84 dwords = 2-way banks, free),
// W2T B-frags from global (L1-hot), 40 MFMA/wave.
__global__ __launch_bounds__(256, 4) void k_gemm2(
        const unsigned short* __restrict__ H,
        const unsigned short* __restrict__ W2T,
        const float* __restrict__ b2,
        unsigned short* __restrict__ ob) {
    __shared__ unsigned short shH[64 * HROW];   // 21504 B
    const int n0 = blockIdx.x * 64;
    const int tid = threadIdx.x;
    const int lane = tid & 63;
    const int w = tid >> 6;

    // async stage: wave w issues idx = w, w+4, ... (21 total x 1024 B)
    {
        const char* gbase = (const char*)H + (size_t)n0 * (HROW * 2);
        for (int idx = w; idx < 21; idx += 4) {
            const char* g = gbase + idx * 1024 + lane * 16;
            char* l = (char*)shH + idx * 1024;   // wave-uniform; HW adds lane*16
            __builtin_amdgcn_global_load_lds(
                (const __attribute__((address_space(1))) unsigned int*)g,
                (__attribute__((address_space(3))) unsigned int*)l,
                16, 0, 0);
        }
    }
    __syncthreads();

    const int c16 = lane & 15;
    const int quad = lane >> 4;
    const int ko = quad * 8;

    f32x4 acc[8];
    #pragma unroll
    for (int t = 0; t < 8; ++t) acc[t] = (f32x4){0.f, 0.f, 0.f, 0.f};

    #pragma unroll
    for (int ks = 0; ks < 5; ++ks) {
        int k0 = ks * 32;
        bf16x8 a = *(const bf16x8*)&shH[(w * 16 + c16) * HROW + k0 + ko];
        #pragma unroll
        for (int t = 0; t < 8; ++t) {
            bf16x8 b = *(const bf16x8*)&W2T[(t * 16 + c16) * KPAD + k0 + ko];
            acc[t] = __builtin_amdgcn_mfma_f32_16x16x32_bf16(a, b, acc[t], 0, 0, 0);
        }
    }

    const int rbase = n0 + w * 16 + quad * 4;
    #pragma unroll
    for (int t = 0; t < 8; ++t) {
        int cc = t * 16 + c16;
        float badd = (t < 4) ? b2[cc] : 0.0f;
        #pragma unroll
        for (int i = 0; i < 4; ++i) {
            int node = rbase + i;
            if (node < N_NODES) ob[(size_t)node * 128 + cc] = f2bf(acc[t][i] + badd);
        }
    }
}

// ---------------- layer-2 pull: one 8-lane group per node, pipelined edge walk ----------
__global__ __launch_bounds__(256) void k_pull(const int2* __restrict__ rows,
                                              const int* __restrict__ csr_src,
                                              const unsigned short* __restrict__ ob,
                                              const float* __restrict__ invd,
                                              float* __restrict__ out) {
    int wid = blockIdx.x * 4 + (threadIdx.x >> 6);
    int lane = threadIdx.x & 63;
    int g = lane >> 3;
    int t = lane & 7;
    int n = wid * 8 + g;
    if (n >= N_NODES) return;
    int2 re = rows[n];

    float acc[8];
    #pragma unroll
    for (int q = 0; q < 8; ++q) acc[q] = 0.0f;

    #pragma unroll 4
    for (int i = re.x; i < re.y; ++i) {
        int s = csr_src[i];
        bf16x8 v = *(const bf16x8*)&ob[(size_t)s * 128 + 64 + t * 8];
        #pragma unroll
        for (int q = 0; q < 8; ++q) acc[q] += bf2f((unsigned short)v[q]);
    }

    float id = invd[n];
    bf16x8 sv = *(const bf16x8*)&ob[(size_t)n * 128 + t * 8];
    f32x4 o0, o1;
    o0[0] = bf2f((unsigned short)sv[0]) + acc[0] * id;
    o0[1] = bf2f((unsigned short)sv[1]) + acc[1] * id;
    o0[2] = bf2f((unsigned short)sv[2]) + acc[2] * id;
    o0[3] = bf2f((unsigned short)sv[3]) + acc[3] * id;
    o1[0] = bf2f((unsigned short)sv[4]) + acc[4] * id;
    o1[1] = bf2f((unsigned short)sv[5]) + acc[5] * id;
    o1[2] = bf2f((unsigned short)sv[6]) + acc[6] * id;
    o1[3] = bf2f((unsigned short)sv[7]) + acc[7] * id;
    *(f32x4*)&out[(size_t)n * OUTF + t * 8]     = o0;
    *(f32x4*)&out[(size_t)n * OUTF + t * 8 + 4] = o1;
}

// ---------------- launcher ----------------

static inline size_t al256(size_t v) { return (v + 255) & ~(size_t)255; }

extern "C" void kernel_launch(void* const* d_in, const int* in_sizes, int n_in,
                              void* d_out, int out_size, void* d_ws, size_t ws_size,
                              hipStream_t stream) {
    const float* x   = (const float*)d_in[0];
    const int*   src = (const int*)d_in[1];
    const int*   dst = (const int*)d_in[2];
    const float* W1s = (const float*)d_in[3];
    const float* W1n = (const float*)d_in[4];
    const float* b1  = (const float*)d_in[5];
    const float* W2s = (const float*)d_in[6];
    const float* W2n = (const float*)d_in[7];
    const float* b2  = (const float*)d_in[8];
    float* out = (float*)d_out;

    char* ws = (char*)d_ws;
    size_t off = 0;
    int2*  rows      = (int2*)(ws + off); off += al256((size_t)N_NODES * 8);
    int*   csr_src   = (int*)(ws + off); off += al256((size_t)NBUK * CAP * 4);
    float* invd      = (float*)(ws + off); off += al256((size_t)N_NODES * 4);
    unsigned short* ob = (unsigned short*)(ws + off); off += al256((size_t)N_NODES * 128 * 2);
    float4* x4       = (float4*)(ws + off); off += al256((size_t)N_NODES * 16);
    unsigned short* H = (unsigned short*)(ws + off); off += al256((size_t)N_PAD * HROW * 2);
    unsigned int* pairbuf = (unsigned int*)(ws + off); off += al256((size_t)NBUK * CAP * 4);
    int*   bukcnt    = (int*)(ws + off); off += al256((size_t)NBUK * 4);
    float* W1t       = (float*)(ws + off); off += al256((size_t)KPAD * 8 * 4);
    unsigned short* W2T = (unsigned short*)(ws + off); off += al256((size_t)128 * KPAD * 2);

    // 1. init: zero bukcnt + pack weights
    k_init<<<1, 256, 0, stream>>>(W1s, W1n, b1, W2s, W2n, W1t, W2T, bukcnt);
    // 2. partition into per-bucket arenas (+ x4 pad)
    k_part<<<NTILE, 256, 0, stream>>>(x, x4, src, dst, bukcnt, pairbuf);
    // 3. per-bucket CSR finish
    k_fine<<<NBUK, 512, 0, stream>>>(bukcnt, pairbuf, rows, invd, csr_src);
    // 4. layer-1 neighbor mean + h materialization
    {
        int waves = (N_NODES + 15) / 16;
        int blocks = (waves * 64 + 255) / 256;
        k_agg1h<<<blocks, 256, 0, stream>>>(rows, csr_src, x4, invd, W1t, H);
    }
    // 5. layer-2 GEMM (global_load_lds staged)
    {
        int blocks = N_PAD / 64;                 // 1563
        k_gemm2<<<blocks, 256, 0, stream>>>(H, W2T, b2, ob);
    }
    // 6. layer-2 pull
    {
        int blocks = (N_NODES + 31) / 32;
        k_pull<<<blocks, 256, 0, stream>>>(rows, csr_src, ob, invd, out);
    }
}

// Round 18
// 135.642 us; speedup vs baseline: 1.4478x; 1.4478x over previous
//
#include <hip/hip_runtime.h>

#define N_NODES 100000
#define N_PAD 100032
#define N_EDGES 1600000
#define HID 150
#define KPAD 160
#define HROW 168                       // shorts per LDS H row (336 B, 16B-aligned)
#define OUTF 64
#define BSH 9
#define BUKN 512
#define NBUK ((N_NODES + BUKN - 1) / BUKN)   // 196 buckets
#define CAP 10240
#define TILE 4096
#define NTILE ((N_EDGES + TILE - 1) / TILE)  // 391 tiles

typedef short bf16x8 __attribute__((ext_vector_type(8)));
typedef float f32x4 __attribute__((ext_vector_type(4)));

__device__ __forceinline__ unsigned short f2bf(float f) {
    union { float f; unsigned u; } v; v.f = f;
    unsigned r = (v.u + 0x7FFFu + ((v.u >> 16) & 1u)) >> 16;
    return (unsigned short)r;
}

__device__ __forceinline__ float bf2f(unsigned short b) {
    union { unsigned u; float f; } v;
    v.u = ((unsigned)b) << 16;
    return v.f;
}

// ---------------- init (1 block): zero bukcnt, pack W1B + W2T ----------------
// W1B[t][lane][j]: layer-1 MFMA B-fragment table (10 col-tiles of 16).
//   b[j] = W1c[k=quad*8+j][col=t*16+c16], zero for quad>0 (K=8 real of 32).
//   W1c rows: 0-2 = W1s, 3 = b1, 4-6 = W1n, 7 = 0.
__global__ __launch_bounds__(256) void k_init(const float* __restrict__ W1s,
                                              const float* __restrict__ W1n,
                                              const float* __restrict__ b1,
                                              const float* __restrict__ W2s,
                                              const float* __restrict__ W2n,
                                              unsigned short* __restrict__ W1B,
                                              unsigned short* __restrict__ W2T,
                                              int* __restrict__ bukcnt) {
    int tid = threadIdx.x;
    if (tid < NBUK) bukcnt[tid] = 0;
    for (int idx = tid; idx < 10 * 64 * 8; idx += 256) {
        int t = idx >> 9;
        int r = idx & 511;
        int ln = r >> 3;
        int j = r & 7;
        int q = ln >> 4;
        int c = t * 16 + (ln & 15);
        float v = 0.0f;
        if (q == 0 && c < HID) {
            if (j < 3)       v = W1s[j * HID + c];
            else if (j == 3) v = b1[c];
            else if (j < 7)  v = W1n[(j - 4) * HID + c];
        }
        W1B[idx] = f2bf(v);
    }
    for (int idx = tid; idx < 128 * KPAD; idx += 256) {
        int c = idx / KPAD, k = idx - c * KPAD;
        float v = 0.0f;
        if (k < HID) v = (c < 64) ? W2s[k * 64 + c] : W2n[k * 64 + (c - 64)];
        W2T[idx] = f2bf(v);
    }
}

// ---------------- partition: x4 pad + bin edges into per-bucket arenas ----------------
__global__ __launch_bounds__(256) void k_part(const float* __restrict__ x,
                                              float4* __restrict__ x4,
                                              const int* __restrict__ src,
                                              const int* __restrict__ dst,
                                              int* __restrict__ bukcnt,
                                              unsigned int* __restrict__ pairbuf) {
    __shared__ int cnt[NBUK];
    __shared__ int gbase[NBUK];
    int tid = threadIdx.x;
    int idx = blockIdx.x * 256 + tid;
    if (idx < N_NODES)
        x4[idx] = make_float4(x[idx * 3 + 0], x[idx * 3 + 1], x[idx * 3 + 2], 0.0f);

    int e0 = blockIdx.x * TILE;
    int n = min(TILE, N_EDGES - e0);

    for (int i = tid; i < NBUK; i += 256) cnt[i] = 0;
    __syncthreads();

    int myb[16];
    int mypos[16];
    unsigned int myv[16];
    #pragma unroll
    for (int j = 0; j < 16; ++j) {
        int ei = tid + j * 256;
        myb[j] = -1;
        if (ei < n) {
            int s = src[e0 + ei];
            int d = dst[e0 + ei];
            int b = d >> BSH;
            myb[j] = b;
            myv[j] = ((unsigned int)(d & (BUKN - 1)) << 17) | (unsigned int)s;
            mypos[j] = atomicAdd(&cnt[b], 1);
        }
    }
    __syncthreads();

    if (tid < NBUK) {
        int c = cnt[tid];
        gbase[tid] = c ? (tid * CAP + atomicAdd(&bukcnt[tid], c)) : 0;
    }
    __syncthreads();

    #pragma unroll
    for (int j = 0; j < 16; ++j) {
        if (myb[j] >= 0)
            pairbuf[gbase[myb[j]] + mypos[j]] = myv[j];
    }
}

// ---------------- per-bucket CSR finish: hist + scan + rows/invd + scatter ----------
__global__ __launch_bounds__(512) void k_fine(const int* __restrict__ bukcnt,
                                              const unsigned int* __restrict__ pairbuf,
                                              int2* __restrict__ rows,
                                              float* __restrict__ invd,
                                              int* __restrict__ csr_src) {
    __shared__ int deg[BUKN];
    __shared__ int sc[BUKN];
    int tid = threadIdx.x;
    int b = blockIdx.x;
    int n0 = b << BSH;
    int lo = b * CAP;
    int hi = lo + bukcnt[b];

    deg[tid] = 0;
    __syncthreads();
    for (int i = lo + tid; i < hi; i += 512)
        atomicAdd(&deg[pairbuf[i] >> 17], 1);
    __syncthreads();

    int d = deg[tid];
    sc[tid] = d;
    __syncthreads();
    for (int o = 1; o < 512; o <<= 1) {
        int a = sc[tid];
        int ap = (tid >= o) ? sc[tid - o] : 0;
        __syncthreads();
        sc[tid] = a + ap;
        __syncthreads();
    }
    int r = lo + sc[tid] - d;
    int node = n0 + tid;
    if (node < N_NODES) {
        rows[node] = make_int2(r, r + d);
        invd[node] = 1.0f / fmaxf((float)d, 1.0f);
    }
    __syncthreads();
    deg[tid] = r;
    __syncthreads();
    for (int i = lo + tid; i < hi; i += 512) {
        unsigned int v = pairbuf[i];
        int dl = v >> 17;
        int ofs = atomicAdd(&deg[dl], 1);
        csr_src[ofs] = (int)(v & 0x1FFFF);
    }
}

// ---------------- layer-1 neighbor mean ----------------
__global__ void k_agg1(const int2* __restrict__ rows, const int* __restrict__ csr_src,
                       const float4* __restrict__ x4, const float* __restrict__ invd,
                       float4* __restrict__ hn4) {
    int wid = (blockIdx.x * blockDim.x + threadIdx.x) >> 6;
    int lane = threadIdx.x & 63;
    int n = wid * 16 + (lane >> 2);
    if (n >= N_NODES) return;
    int sub = lane & 3;
    int2 re = rows[n];
    float s0 = 0.f, s1 = 0.f, s2 = 0.f;
    for (int i = re.x + sub; i < re.y; i += 4) {
        float4 v = x4[csr_src[i]];
        s0 += v.x; s1 += v.y; s2 += v.z;
    }
    s0 += __shfl_xor(s0, 1, 64); s0 += __shfl_xor(s0, 2, 64);
    s1 += __shfl_xor(s1, 1, 64); s1 += __shfl_xor(s1, 2, 64);
    s2 += __shfl_xor(s2, 1, 64); s2 += __shfl_xor(s2, 2, 64);
    if (sub == 0) {
        float id = invd[n];
        hn4[n] = make_float4(s0 * id, s1 * id, s2 * id, 0.0f);
    }
}

// ---------------- fused layer1(MFMA) + layer2(MFMA) GEMM ----------------
// Per wave (16 nodes): layer-1 Z = A8 @ W1c via 10 MFMAs (K=8 zero-padded to 32),
// relu -> bf16 -> own LDS rows (no cross-wave sharing, NO barrier), then layer-2:
// 40 MFMAs vs W2T. Writes ob[node][0..63]=self+b2, [64..127]=p.
__global__ __launch_bounds__(256, 2) void k_gemm(
        const float4* __restrict__ x4, const float4* __restrict__ hn4,
        const unsigned short* __restrict__ W1B,
        const unsigned short* __restrict__ W2T,
        const float* __restrict__ b2,
        unsigned short* __restrict__ ob) {
    __shared__ unsigned short shH[64 * HROW];   // 21504 B
    const int n0 = blockIdx.x * 64;
    const int tid = threadIdx.x;
    const int lane = tid & 63;
    const int w = tid >> 6;
    const int c16 = lane & 15;
    const int quad = lane >> 4;
    const int nb = w * 16;                       // wave's rows in tile

    // ---- layer-1 A-fragment: quad 0 holds (xs0,xs1,xs2,1,xn0,xn1,xn2,0) bf16
    bf16x8 a8 = (bf16x8){0, 0, 0, 0, 0, 0, 0, 0};
    if (quad == 0) {
        int node = n0 + nb + c16;
        float4 xs = make_float4(0.f, 0.f, 0.f, 0.f);
        float4 xn = make_float4(0.f, 0.f, 0.f, 0.f);
        if (node < N_NODES) { xs = x4[node]; xn = hn4[node]; }
        union { unsigned int u[4]; bf16x8 v; } t;
        t.u[0] = (unsigned int)f2bf(xs.x) | ((unsigned int)f2bf(xs.y) << 16);
        t.u[1] = (unsigned int)f2bf(xs.z) | (0x3F80u << 16);   // bf16(1.0)
        t.u[2] = (unsigned int)f2bf(xn.x) | ((unsigned int)f2bf(xn.y) << 16);
        t.u[3] = (unsigned int)f2bf(xn.z);
        a8 = t.v;
    }

    // ---- layer-1: 10 MFMAs -> Z[16][160]; relu -> bf16 -> LDS (own rows only)
    #pragma unroll
    for (int t10 = 0; t10 < 10; ++t10) {
        bf16x8 b = *(const bf16x8*)&W1B[(t10 * 64 + lane) * 8];
        f32x4 z = __builtin_amdgcn_mfma_f32_16x16x32_bf16(
                      a8, b, (f32x4){0.f, 0.f, 0.f, 0.f}, 0, 0, 0);
        // lane holds Z[row = nb+quad*4+i][col = t10*16+c16]
        #pragma unroll
        for (int i = 0; i < 4; ++i) {
            float h = fmaxf(z[i], 0.0f);
            shH[(nb + quad * 4 + i) * HROW + t10 * 16 + c16] = f2bf(h);
        }
    }
    // no __syncthreads: each wave reads only rows it wrote (lgkmcnt handled by compiler)

    // ---- layer-2: 5 K-steps x 8 col-tiles
    const int ko = quad * 8;
    f32x4 acc[8];
    #pragma unroll
    for (int t = 0; t < 8; ++t) acc[t] = (f32x4){0.f, 0.f, 0.f, 0.f};

    #pragma unroll
    for (int ks = 0; ks < 5; ++ks) {
        int k0 = ks * 32;
        bf16x8 a = *(const bf16x8*)&shH[(nb + c16) * HROW + k0 + ko];
        #pragma unroll
        for (int t = 0; t < 8; ++t) {
            bf16x8 b = *(const bf16x8*)&W2T[(t * 16 + c16) * KPAD + k0 + ko];
            acc[t] = __builtin_amdgcn_mfma_f32_16x16x32_bf16(a, b, acc[t], 0, 0, 0);
        }
    }

    const int rbase = n0 + nb + quad * 4;
    #pragma unroll
    for (int t = 0; t < 8; ++t) {
        int cc = t * 16 + c16;
        float badd = (t < 4) ? b2[cc] : 0.0f;
        #pragma unroll
        for (int i = 0; i < 4; ++i) {
            int node = rbase + i;
            if (node < N_NODES) ob[(size_t)node * 128 + cc] = f2bf(acc[t][i] + badd);
        }
    }
}

// ---------------- layer-2 pull: one 8-lane group per node, pipelined edge walk ----------
__global__ __launch_bounds__(256) void k_pull(const int2* __restrict__ rows,
                                              const int* __restrict__ csr_src,
                                              const unsigned short* __restrict__ ob,
                                              const float* __restrict__ invd,
                                              float* __restrict__ out) {
    int wid = blockIdx.x * 4 + (threadIdx.x >> 6);
    int lane = threadIdx.x & 63;
    int g = lane >> 3;
    int t = lane & 7;
    int n = wid * 8 + g;
    if (n >= N_NODES) return;
    int2 re = rows[n];

    float acc[8];
    #pragma unroll
    for (int q = 0; q < 8; ++q) acc[q] = 0.0f;

    #pragma unroll 4
    for (int i = re.x; i < re.y; ++i) {
        int s = csr_src[i];
        bf16x8 v = *(const bf16x8*)&ob[(size_t)s * 128 + 64 + t * 8];
        #pragma unroll
        for (int q = 0; q < 8; ++q) acc[q] += bf2f((unsigned short)v[q]);
    }

    float id = invd[n];
    bf16x8 sv = *(const bf16x8*)&ob[(size_t)n * 128 + t * 8];
    f32x4 o0, o1;
    o0[0] = bf2f((unsigned short)sv[0]) + acc[0] * id;
    o0[1] = bf2f((unsigned short)sv[1]) + acc[1] * id;
    o0[2] = bf2f((unsigned short)sv[2]) + acc[2] * id;
    o0[3] = bf2f((unsigned short)sv[3]) + acc[3] * id;
    o1[0] = bf2f((unsigned short)sv[4]) + acc[4] * id;
    o1[1] = bf2f((unsigned short)sv[5]) + acc[5] * id;
    o1[2] = bf2f((unsigned short)sv[6]) + acc[6] * id;
    o1[3] = bf2f((unsigned short)sv[7]) + acc[7] * id;
    *(f32x4*)&out[(size_t)n * OUTF + t * 8]     = o0;
    *(f32x4*)&out[(size_t)n * OUTF + t * 8 + 4] = o1;
}

// ---------------- launcher ----------------

static inline size_t al256(size_t v) { return (v + 255) & ~(size_t)255; }

extern "C" void kernel_launch(void* const* d_in, const int* in_sizes, int n_in,
                              void* d_out, int out_size, void* d_ws, size_t ws_size,
                              hipStream_t stream) {
    const float* x   = (const float*)d_in[0];
    const int*   src = (const int*)d_in[1];
    const int*   dst = (const int*)d_in[2];
    const float* W1s = (const float*)d_in[3];
    const float* W1n = (const float*)d_in[4];
    const float* b1  = (const float*)d_in[5];
    const float* W2s = (const float*)d_in[6];
    const float* W2n = (const float*)d_in[7];
    const float* b2  = (const float*)d_in[8];
    float* out = (float*)d_out;

    char* ws = (char*)d_ws;
    size_t off = 0;
    int2*  rows      = (int2*)(ws + off); off += al256((size_t)N_NODES * 8);
    int*   csr_src   = (int*)(ws + off); off += al256((size_t)NBUK * CAP * 4);
    float* invd      = (float*)(ws + off); off += al256((size_t)N_NODES * 4);
    unsigned short* ob = (unsigned short*)(ws + off); off += al256((size_t)N_NODES * 128 * 2);
    float4* x4       = (float4*)(ws + off); off += al256((size_t)N_NODES * 16);
    float4* hn4      = (float4*)(ws + off); off += al256((size_t)N_NODES * 16);
    unsigned int* pairbuf = (unsigned int*)(ws + off); off += al256((size_t)NBUK * CAP * 4);
    int*   bukcnt    = (int*)(ws + off); off += al256((size_t)NBUK * 4);
    unsigned short* W1B = (unsigned short*)(ws + off); off += al256((size_t)10 * 64 * 8 * 2);
    unsigned short* W2T = (unsigned short*)(ws + off); off += al256((size_t)128 * KPAD * 2);

    // 1. init: zero bukcnt + pack W1B/W2T
    k_init<<<1, 256, 0, stream>>>(W1s, W1n, b1, W2s, W2n, W1B, W2T, bukcnt);
    // 2. partition into per-bucket arenas (+ x4 pad)
    k_part<<<NTILE, 256, 0, stream>>>(x, x4, src, dst, bukcnt, pairbuf);
    // 3. per-bucket CSR finish
    k_fine<<<NBUK, 512, 0, stream>>>(bukcnt, pairbuf, rows, invd, csr_src);
    // 4. layer-1 neighbor mean
    {
        int waves = (N_NODES + 15) / 16;
        int blocks = (waves * 64 + 255) / 256;
        k_agg1<<<blocks, 256, 0, stream>>>(rows, csr_src, x4, invd, hn4);
    }
    // 5. fused layer1(MFMA)+layer2(MFMA) GEMM
    {
        int blocks = N_PAD / 64;                 // 1563
        k_gemm<<<blocks, 256, 0, stream>>>(x4, hn4, W1B, W2T, b2, ob);
    }
    // 6. layer-2 pull
    {
        int blocks = (N_NODES + 31) / 32;
        k_pull<<<blocks, 256, 0, stream>>>(rows, csr_src, ob, invd, out);
    }
}

// Round 19
// 115.818 us; speedup vs baseline: 1.6957x; 1.1712x over previous
//
#include <hip/hip_runtime.h>

#define N_NODES 100000
#define N_PAD 100032
#define N_EDGES 1600000
#define HID 150
#define KPAD 160
#define HROW 168
#define OUTF 64
#define BSH 9
#define BUKN 512
#define NBUK ((N_NODES + BUKN - 1) / BUKN)   // 196 buckets
#define CAP 10240
#define TILE 4096
#define NTILE ((N_EDGES + TILE - 1) / TILE)  // 391 tiles
#define W1B_N (10 * 64 * 8)                  // 5120
#define W2T_N (128 * KPAD)                   // 20480

typedef short bf16x8 __attribute__((ext_vector_type(8)));
typedef float f32x4 __attribute__((ext_vector_type(4)));

__device__ __forceinline__ unsigned short f2bf(float f) {
    union { float f; unsigned u; } v; v.f = f;
    unsigned r = (v.u + 0x7FFFu + ((v.u >> 16) & 1u)) >> 16;
    return (unsigned short)r;
}

__device__ __forceinline__ float bf2f(unsigned short b) {
    union { unsigned u; float f; } v;
    v.u = ((unsigned)b) << 16;
    return v.f;
}

// ---------------- init0 (1 tiny block): zero bukcnt ----------------
__global__ __launch_bounds__(256) void k_init0(int* __restrict__ bukcnt) {
    int tid = threadIdx.x;
    if (tid < NBUK) bukcnt[tid] = 0;
}

// ---------------- partition: weight packing (blocks 0-99) + x4 pad + edge binning ------
__global__ __launch_bounds__(256) void k_part(const float* __restrict__ x,
                                              float4* __restrict__ x4,
                                              const int* __restrict__ src,
                                              const int* __restrict__ dst,
                                              int* __restrict__ bukcnt,
                                              unsigned int* __restrict__ pairbuf,
                                              const float* __restrict__ W1s,
                                              const float* __restrict__ W1n,
                                              const float* __restrict__ b1,
                                              const float* __restrict__ W2s,
                                              const float* __restrict__ W2n,
                                              unsigned short* __restrict__ W1B,
                                              unsigned short* __restrict__ W2T) {
    __shared__ int cnt[NBUK];
    __shared__ int gbase[NBUK];
    int tid = threadIdx.x;
    int idx = blockIdx.x * 256 + tid;

    // distributed weight packing: first 100 blocks, 1 element/thread
    if (idx < W1B_N) {
        int t = idx >> 9;
        int r = idx & 511;
        int ln = r >> 3;
        int j = r & 7;
        int q = ln >> 4;
        int c = t * 16 + (ln & 15);
        float v = 0.0f;
        if (q == 0 && c < HID) {
            if (j < 3)       v = W1s[j * HID + c];
            else if (j == 3) v = b1[c];
            else if (j < 7)  v = W1n[(j - 4) * HID + c];
        }
        W1B[idx] = f2bf(v);
    } else if (idx < W1B_N + W2T_N) {
        int i2 = idx - W1B_N;
        int c = i2 / KPAD, k = i2 - c * KPAD;
        float v = 0.0f;
        if (k < HID) v = (c < 64) ? W2s[k * 64 + c] : W2n[k * 64 + (c - 64)];
        W2T[i2] = f2bf(v);
    }

    if (idx < N_NODES)
        x4[idx] = make_float4(x[idx * 3 + 0], x[idx * 3 + 1], x[idx * 3 + 2], 0.0f);

    int e0 = blockIdx.x * TILE;
    int n = min(TILE, N_EDGES - e0);

    for (int i = tid; i < NBUK; i += 256) cnt[i] = 0;
    __syncthreads();

    int myb[16];
    int mypos[16];
    unsigned int myv[16];
    #pragma unroll
    for (int j = 0; j < 16; ++j) {
        int ei = tid + j * 256;
        myb[j] = -1;
        if (ei < n) {
            int s = src[e0 + ei];
            int d = dst[e0 + ei];
            int b = d >> BSH;
            myb[j] = b;
            myv[j] = ((unsigned int)(d & (BUKN - 1)) << 17) | (unsigned int)s;
            mypos[j] = atomicAdd(&cnt[b], 1);
        }
    }
    __syncthreads();

    if (tid < NBUK) {
        int c = cnt[tid];
        gbase[tid] = c ? (tid * CAP + atomicAdd(&bukcnt[tid], c)) : 0;
    }
    __syncthreads();

    #pragma unroll
    for (int j = 0; j < 16; ++j) {
        if (myb[j] >= 0)
            pairbuf[gbase[myb[j]] + mypos[j]] = myv[j];
    }
}

// ---------------- per-bucket CSR finish: hist + scan + rows/invd + scatter ----------
__global__ __launch_bounds__(512) void k_fine(const int* __restrict__ bukcnt,
                                              const unsigned int* __restrict__ pairbuf,
                                              int2* __restrict__ rows,
                                              float* __restrict__ invd,
                                              int* __restrict__ csr_src) {
    __shared__ int deg[BUKN];
    __shared__ int sc[BUKN];
    int tid = threadIdx.x;
    int b = blockIdx.x;
    int n0 = b << BSH;
    int lo = b * CAP;
    int hi = lo + bukcnt[b];

    deg[tid] = 0;
    __syncthreads();
    for (int i = lo + tid; i < hi; i += 512)
        atomicAdd(&deg[pairbuf[i] >> 17], 1);
    __syncthreads();

    int d = deg[tid];
    sc[tid] = d;
    __syncthreads();
    for (int o = 1; o < 512; o <<= 1) {
        int a = sc[tid];
        int ap = (tid >= o) ? sc[tid - o] : 0;
        __syncthreads();
        sc[tid] = a + ap;
        __syncthreads();
    }
    int r = lo + sc[tid] - d;
    int node = n0 + tid;
    if (node < N_NODES) {
        rows[node] = make_int2(r, r + d);
        invd[node] = 1.0f / fmaxf((float)d, 1.0f);
    }
    __syncthreads();
    deg[tid] = r;
    __syncthreads();
    for (int i = lo + tid; i < hi; i += 512) {
        unsigned int v = pairbuf[i];
        int dl = v >> 17;
        int ofs = atomicAdd(&deg[dl], 1);
        csr_src[ofs] = (int)(v & 0x1FFFF);
    }
}

// ---------------- fused agg1 + layer1(MFMA) + layer2(MFMA) GEMM ----------------
// Per wave (16 nodes): (a) neighbor mean: 4 lanes/node gather + width-4 butterfly;
// (b) layer-1 Z = A8 @ W1c via 10 MFMAs (K=8 zero-padded); relu -> bf16 -> own LDS
// rows (no barrier); (c) layer-2: 40 MFMAs vs W2T.
// ob[node][0..63] = self+b2, [64..127] = p.
__global__ __launch_bounds__(256, 2) void k_gemm(
        const float4* __restrict__ x4,
        const int2* __restrict__ rows,
        const int* __restrict__ csr_src,
        const float* __restrict__ invd,
        const unsigned short* __restrict__ W1B,
        const unsigned short* __restrict__ W2T,
        const float* __restrict__ b2,
        unsigned short* __restrict__ ob) {
    __shared__ unsigned short shH[64 * HROW];   // 21504 B
    const int n0 = blockIdx.x * 64;
    const int tid = threadIdx.x;
    const int lane = tid & 63;
    const int w = tid >> 6;
    const int c16 = lane & 15;
    const int quad = lane >> 4;
    const int nb = w * 16;

    // ---- (a) neighbor mean for this wave's 16 nodes: group j = lane>>2, sub = lane&3
    float s0 = 0.f, s1 = 0.f, s2 = 0.f;
    {
        int j = lane >> 2;
        int sub = lane & 3;
        int nj = n0 + nb + j;
        if (nj < N_NODES) {
            int2 re = rows[nj];
            for (int i = re.x + sub; i < re.y; i += 4) {
                float4 v = x4[csr_src[i]];
                s0 += v.x; s1 += v.y; s2 += v.z;
            }
        }
        s0 += __shfl_xor(s0, 1, 64); s0 += __shfl_xor(s0, 2, 64);
        s1 += __shfl_xor(s1, 1, 64); s1 += __shfl_xor(s1, 2, 64);
        s2 += __shfl_xor(s2, 1, 64); s2 += __shfl_xor(s2, 2, 64);
        float id = (nj < N_NODES) ? invd[nj] : 0.0f;
        s0 *= id; s1 *= id; s2 *= id;
    }
    // redistribute: lane l needs node (l&15)'s mean, held by lanes (l&15)*4..+3
    float xn0 = __shfl(s0, c16 * 4, 64);
    float xn1 = __shfl(s1, c16 * 4, 64);
    float xn2 = __shfl(s2, c16 * 4, 64);

    // ---- (b) layer-1 A-fragment: quad 0 holds (xs0,xs1,xs2,1,xn0,xn1,xn2,0)
    bf16x8 a8 = (bf16x8){0, 0, 0, 0, 0, 0, 0, 0};
    if (quad == 0) {
        int node = n0 + nb + c16;
        float4 xs = make_float4(0.f, 0.f, 0.f, 0.f);
        if (node < N_NODES) xs = x4[node];
        union { unsigned int u[4]; bf16x8 v; } t;
        t.u[0] = (unsigned int)f2bf(xs.x) | ((unsigned int)f2bf(xs.y) << 16);
        t.u[1] = (unsigned int)f2bf(xs.z) | (0x3F80u << 16);   // bf16(1.0)
        t.u[2] = (unsigned int)f2bf(xn0) | ((unsigned int)f2bf(xn1) << 16);
        t.u[3] = (unsigned int)f2bf(xn2);
        a8 = t.v;
    }

    #pragma unroll
    for (int t10 = 0; t10 < 10; ++t10) {
        bf16x8 b = *(const bf16x8*)&W1B[(t10 * 64 + lane) * 8];
        f32x4 z = __builtin_amdgcn_mfma_f32_16x16x32_bf16(
                      a8, b, (f32x4){0.f, 0.f, 0.f, 0.f}, 0, 0, 0);
        #pragma unroll
        for (int i = 0; i < 4; ++i) {
            float h = fmaxf(z[i], 0.0f);
            shH[(nb + quad * 4 + i) * HROW + t10 * 16 + c16] = f2bf(h);
        }
    }
    // no __syncthreads: each wave reads only rows it wrote

    // ---- (c) layer-2: 5 K-steps x 8 col-tiles
    const int ko = quad * 8;
    f32x4 acc[8];
    #pragma unroll
    for (int t = 0; t < 8; ++t) acc[t] = (f32x4){0.f, 0.f, 0.f, 0.f};

    #pragma unroll
    for (int ks = 0; ks < 5; ++ks) {
        int k0 = ks * 32;
        bf16x8 a = *(const bf16x8*)&shH[(nb + c16) * HROW + k0 + ko];
        #pragma unroll
        for (int t = 0; t < 8; ++t) {
            bf16x8 b = *(const bf16x8*)&W2T[(t * 16 + c16) * KPAD + k0 + ko];
            acc[t] = __builtin_amdgcn_mfma_f32_16x16x32_bf16(a, b, acc[t], 0, 0, 0);
        }
    }

    const int rbase = n0 + nb + quad * 4;
    #pragma unroll
    for (int t = 0; t < 8; ++t) {
        int cc = t * 16 + c16;
        float badd = (t < 4) ? b2[cc] : 0.0f;
        #pragma unroll
        for (int i = 0; i < 4; ++i) {
            int node = rbase + i;
            if (node < N_NODES) ob[(size_t)node * 128 + cc] = f2bf(acc[t][i] + badd);
        }
    }
}

// ---------------- layer-2 pull: one 8-lane group per node, pipelined edge walk ----------
__global__ __launch_bounds__(256) void k_pull(const int2* __restrict__ rows,
                                              const int* __restrict__ csr_src,
                                              const unsigned short* __restrict__ ob,
                                              const float* __restrict__ invd,
                                              float* __restrict__ out) {
    int wid = blockIdx.x * 4 + (threadIdx.x >> 6);
    int lane = threadIdx.x & 63;
    int g = lane >> 3;
    int t = lane & 7;
    int n = wid * 8 + g;
    if (n >= N_NODES) return;
    int2 re = rows[n];

    float acc[8];
    #pragma unroll
    for (int q = 0; q < 8; ++q) acc[q] = 0.0f;

    #pragma unroll 4
    for (int i = re.x; i < re.y; ++i) {
        int s = csr_src[i];
        bf16x8 v = *(const bf16x8*)&ob[(size_t)s * 128 + 64 + t * 8];
        #pragma unroll
        for (int q = 0; q < 8; ++q) acc[q] += bf2f((unsigned short)v[q]);
    }

    float id = invd[n];
    bf16x8 sv = *(const bf16x8*)&ob[(size_t)n * 128 + t * 8];
    f32x4 o0, o1;
    o0[0] = bf2f((unsigned short)sv[0]) + acc[0] * id;
    o0[1] = bf2f((unsigned short)sv[1]) + acc[1] * id;
    o0[2] = bf2f((unsigned short)sv[2]) + acc[2] * id;
    o0[3] = bf2f((unsigned short)sv[3]) + acc[3] * id;
    o1[0] = bf2f((unsigned short)sv[4]) + acc[4] * id;
    o1[1] = bf2f((unsigned short)sv[5]) + acc[5] * id;
    o1[2] = bf2f((unsigned short)sv[6]) + acc[6] * id;
    o1[3] = bf2f((unsigned short)sv[7]) + acc[7] * id;
    *(f32x4*)&out[(size_t)n * OUTF + t * 8]     = o0;
    *(f32x4*)&out[(size_t)n * OUTF + t * 8 + 4] = o1;
}

// ---------------- launcher ----------------

static inline size_t al256(size_t v) { return (v + 255) & ~(size_t)255; }

extern "C" void kernel_launch(void* const* d_in, const int* in_sizes, int n_in,
                              void* d_out, int out_size, void* d_ws, size_t ws_size,
                              hipStream_t stream) {
    const float* x   = (const float*)d_in[0];
    const int*   src = (const int*)d_in[1];
    const int*   dst = (const int*)d_in[2];
    const float* W1s = (const float*)d_in[3];
    const float* W1n = (const float*)d_in[4];
    const float* b1  = (const float*)d_in[5];
    const float* W2s = (const float*)d_in[6];
    const float* W2n = (const float*)d_in[7];
    const float* b2  = (const float*)d_in[8];
    float* out = (float*)d_out;

    char* ws = (char*)d_ws;
    size_t off = 0;
    int2*  rows      = (int2*)(ws + off); off += al256((size_t)N_NODES * 8);
    int*   csr_src   = (int*)(ws + off); off += al256((size_t)NBUK * CAP * 4);
    float* invd      = (float*)(ws + off); off += al256((size_t)N_NODES * 4);
    unsigned short* ob = (unsigned short*)(ws + off); off += al256((size_t)N_NODES * 128 * 2);
    float4* x4       = (float4*)(ws + off); off += al256((size_t)N_NODES * 16);
    unsigned int* pairbuf = (unsigned int*)(ws + off); off += al256((size_t)NBUK * CAP * 4);
    int*   bukcnt    = (int*)(ws + off); off += al256((size_t)NBUK * 4);
    unsigned short* W1B = (unsigned short*)(ws + off); off += al256((size_t)W1B_N * 2);
    unsigned short* W2T = (unsigned short*)(ws + off); off += al256((size_t)W2T_N * 2);

    // 1. zero bukcnt (tiny)
    k_init0<<<1, 256, 0, stream>>>(bukcnt);
    // 2. partition (+ distributed weight packing + x4 pad)
    k_part<<<NTILE, 256, 0, stream>>>(x, x4, src, dst, bukcnt, pairbuf,
                                      W1s, W1n, b1, W2s, W2n, W1B, W2T);
    // 3. per-bucket CSR finish
    k_fine<<<NBUK, 512, 0, stream>>>(bukcnt, pairbuf, rows, invd, csr_src);
    // 4. fused agg1 + layer1(MFMA) + layer2(MFMA)
    {
        int blocks = N_PAD / 64;                 // 1563
        k_gemm<<<blocks, 256, 0, stream>>>(x4, rows, csr_src, invd, W1B, W2T, b2, ob);
    }
    // 5. layer-2 pull
    {
        int blocks = (N_NODES + 31) / 32;
        k_pull<<<blocks, 256, 0, stream>>>(rows, csr_src, ob, invd, out);
    }
}

// Round 20
// 112.398 us; speedup vs baseline: 1.7473x; 1.0304x over previous
//
#include <hip/hip_runtime.h>

#define N_NODES 100000
#define N_PAD 100032
#define N_EDGES 1600000
#define HID 150
#define KPAD 160
#define HROW 168
#define OUTF 64
#define BSH 9
#define BUKN 512
#define NBUK ((N_NODES + BUKN - 1) / BUKN)   // 196 buckets
#define CAP 10240
#define TILE 4096
#define NTILE ((N_EDGES + TILE - 1) / TILE)  // 391 tiles
#define W1B_N (10 * 64 * 8)                  // 5120
#define W2T_N (128 * KPAD)                   // 20480

typedef short bf16x8 __attribute__((ext_vector_type(8)));
typedef float f32x4 __attribute__((ext_vector_type(4)));

__device__ __forceinline__ unsigned short f2bf(float f) {
    union { float f; unsigned u; } v; v.f = f;
    unsigned r = (v.u + 0x7FFFu + ((v.u >> 16) & 1u)) >> 16;
    return (unsigned short)r;
}

__device__ __forceinline__ float bf2f(unsigned short b) {
    union { unsigned u; float f; } v;
    v.u = ((unsigned)b) << 16;
    return v.f;
}

// ---------------- init0 (1 tiny block): zero bukcnt ----------------
__global__ __launch_bounds__(256) void k_init0(int* __restrict__ bukcnt) {
    int tid = threadIdx.x;
    if (tid < NBUK) bukcnt[tid] = 0;
}

// ---------------- partition: weight packing (blocks 0-99) + x4 pad + edge binning ------
__global__ __launch_bounds__(256) void k_part(const float* __restrict__ x,
                                              float4* __restrict__ x4,
                                              const int* __restrict__ src,
                                              const int* __restrict__ dst,
                                              int* __restrict__ bukcnt,
                                              unsigned int* __restrict__ pairbuf,
                                              const float* __restrict__ W1s,
                                              const float* __restrict__ W1n,
                                              const float* __restrict__ b1,
                                              const float* __restrict__ W2s,
                                              const float* __restrict__ W2n,
                                              unsigned short* __restrict__ W1B,
                                              unsigned short* __restrict__ W2T) {
    __shared__ int cnt[NBUK];
    __shared__ int gbase[NBUK];
    int tid = threadIdx.x;
    int idx = blockIdx.x * 256 + tid;

    if (idx < W1B_N) {
        int t = idx >> 9;
        int r = idx & 511;
        int ln = r >> 3;
        int j = r & 7;
        int q = ln >> 4;
        int c = t * 16 + (ln & 15);
        float v = 0.0f;
        if (q == 0 && c < HID) {
            if (j < 3)       v = W1s[j * HID + c];
            else if (j == 3) v = b1[c];
            else if (j < 7)  v = W1n[(j - 4) * HID + c];
        }
        W1B[idx] = f2bf(v);
    } else if (idx < W1B_N + W2T_N) {
        int i2 = idx - W1B_N;
        int c = i2 / KPAD, k = i2 - c * KPAD;
        float v = 0.0f;
        if (k < HID) v = (c < 64) ? W2s[k * 64 + c] : W2n[k * 64 + (c - 64)];
        W2T[i2] = f2bf(v);
    }

    if (idx < N_NODES)
        x4[idx] = make_float4(x[idx * 3 + 0], x[idx * 3 + 1], x[idx * 3 + 2], 0.0f);

    int e0 = blockIdx.x * TILE;
    int n = min(TILE, N_EDGES - e0);

    for (int i = tid; i < NBUK; i += 256) cnt[i] = 0;
    __syncthreads();

    int myb[16];
    int mypos[16];
    unsigned int myv[16];
    #pragma unroll
    for (int j = 0; j < 16; ++j) {
        int ei = tid + j * 256;
        myb[j] = -1;
        if (ei < n) {
            int s = src[e0 + ei];
            int d = dst[e0 + ei];
            int b = d >> BSH;
            myb[j] = b;
            myv[j] = ((unsigned int)(d & (BUKN - 1)) << 17) | (unsigned int)s;
            mypos[j] = atomicAdd(&cnt[b], 1);
        }
    }
    __syncthreads();

    if (tid < NBUK) {
        int c = cnt[tid];
        gbase[tid] = c ? (tid * CAP + atomicAdd(&bukcnt[tid], c)) : 0;
    }
    __syncthreads();

    #pragma unroll
    for (int j = 0; j < 16; ++j) {
        if (myb[j] >= 0)
            pairbuf[gbase[myb[j]] + mypos[j]] = myv[j];
    }
}

// ---------------- per-bucket CSR finish: hist + scan + rows/invd + scatter ----------
__global__ __launch_bounds__(512) void k_fine(const int* __restrict__ bukcnt,
                                              const unsigned int* __restrict__ pairbuf,
                                              int2* __restrict__ rows,
                                              float* __restrict__ invd,
                                              int* __restrict__ csr_src) {
    __shared__ int deg[BUKN];
    __shared__ int sc[BUKN];
    int tid = threadIdx.x;
    int b = blockIdx.x;
    int n0 = b << BSH;
    int lo = b * CAP;
    int hi = lo + bukcnt[b];

    deg[tid] = 0;
    __syncthreads();
    for (int i = lo + tid; i < hi; i += 512)
        atomicAdd(&deg[pairbuf[i] >> 17], 1);
    __syncthreads();

    int d = deg[tid];
    sc[tid] = d;
    __syncthreads();
    for (int o = 1; o < 512; o <<= 1) {
        int a = sc[tid];
        int ap = (tid >= o) ? sc[tid - o] : 0;
        __syncthreads();
        sc[tid] = a + ap;
        __syncthreads();
    }
    int r = lo + sc[tid] - d;
    int node = n0 + tid;
    if (node < N_NODES) {
        rows[node] = make_int2(r, r + d);
        invd[node] = 1.0f / fmaxf((float)d, 1.0f);
    }
    __syncthreads();
    deg[tid] = r;
    __syncthreads();
    for (int i = lo + tid; i < hi; i += 512) {
        unsigned int v = pairbuf[i];
        int dl = v >> 17;
        int ofs = atomicAdd(&deg[dl], 1);
        csr_src[ofs] = (int)(v & 0x1FFFF);
    }
}

// ---------------- fused agg1 + layer1(MFMA) + layer2(MFMA), 2 waves/tile ----------------
// Block = 32 nodes = 2 tiles x 2 waves. Wave (tile, h):
//  (a) gather 8 nodes with 8 lanes/node (serial iters ~deg/8), butterfly, means->shXN
//  (b) layer-1: both waves build a8; wave h does t10 = h*5..h*5+4 -> shH cols h*80..+79
//  (c) layer-2: wave h computes col-tiles h*4..h*4+3 (cols h*64..h*64+63)
__global__ __launch_bounds__(256, 2) void k_gemm(
        const float4* __restrict__ x4,
        const int2* __restrict__ rows,
        const int* __restrict__ csr_src,
        const float* __restrict__ invd,
        const unsigned short* __restrict__ W1B,
        const unsigned short* __restrict__ W2T,
        const float* __restrict__ b2,
        unsigned short* __restrict__ ob) {
    __shared__ unsigned short shH[32 * HROW];   // 10752 B
    __shared__ float shXN[32][3];
    const int blk_n0 = blockIdx.x * 32;
    const int tid = threadIdx.x;
    const int lane = tid & 63;
    const int w = tid >> 6;       // 0..3
    const int tile = w >> 1;      // 0..1
    const int h = w & 1;          // half
    const int c16 = lane & 15;
    const int quad = lane >> 4;
    const int tn0 = tile * 16;    // tile row base within block

    // ---- (a) gather: 8 lanes/node, 8 nodes/wave
    {
        int j = lane >> 3;        // 0..7
        int sub = lane & 7;
        int nj = blk_n0 + tn0 + h * 8 + j;
        float s0 = 0.f, s1 = 0.f, s2 = 0.f;
        if (nj < N_NODES) {
            int2 re = rows[nj];
            for (int i = re.x + sub; i < re.y; i += 8) {
                float4 v = x4[csr_src[i]];
                s0 += v.x; s1 += v.y; s2 += v.z;
            }
        }
        s0 += __shfl_xor(s0, 1, 64); s0 += __shfl_xor(s0, 2, 64); s0 += __shfl_xor(s0, 4, 64);
        s1 += __shfl_xor(s1, 1, 64); s1 += __shfl_xor(s1, 2, 64); s1 += __shfl_xor(s1, 4, 64);
        s2 += __shfl_xor(s2, 1, 64); s2 += __shfl_xor(s2, 2, 64); s2 += __shfl_xor(s2, 4, 64);
        if (sub == 0) {
            float id = (nj < N_NODES) ? invd[nj] : 0.0f;
            int rloc = tn0 + h * 8 + j;
            shXN[rloc][0] = s0 * id;
            shXN[rloc][1] = s1 * id;
            shXN[rloc][2] = s2 * id;
        }
    }
    __syncthreads();

    // ---- (b) layer-1 A-fragment + 5 MFMAs per wave
    bf16x8 a8 = (bf16x8){0, 0, 0, 0, 0, 0, 0, 0};
    if (quad == 0) {
        int node = blk_n0 + tn0 + c16;
        float4 xs = make_float4(0.f, 0.f, 0.f, 0.f);
        if (node < N_NODES) xs = x4[node];
        float xn0 = shXN[tn0 + c16][0];
        float xn1 = shXN[tn0 + c16][1];
        float xn2 = shXN[tn0 + c16][2];
        union { unsigned int u[4]; bf16x8 v; } t;
        t.u[0] = (unsigned int)f2bf(xs.x) | ((unsigned int)f2bf(xs.y) << 16);
        t.u[1] = (unsigned int)f2bf(xs.z) | (0x3F80u << 16);   // bf16(1.0)
        t.u[2] = (unsigned int)f2bf(xn0) | ((unsigned int)f2bf(xn1) << 16);
        t.u[3] = (unsigned int)f2bf(xn2);
        a8 = t.v;
    }

    #pragma unroll
    for (int m = 0; m < 5; ++m) {
        int t10 = h * 5 + m;
        bf16x8 b = *(const bf16x8*)&W1B[(t10 * 64 + lane) * 8];
        f32x4 z = __builtin_amdgcn_mfma_f32_16x16x32_bf16(
                      a8, b, (f32x4){0.f, 0.f, 0.f, 0.f}, 0, 0, 0);
        #pragma unroll
        for (int i = 0; i < 4; ++i) {
            float hh = fmaxf(z[i], 0.0f);
            shH[(tn0 + quad * 4 + i) * HROW + t10 * 16 + c16] = f2bf(hh);
        }
    }
    __syncthreads();

    // ---- (c) layer-2: 4 col-tiles for this half
    const int ko = quad * 8;
    f32x4 acc[4];
    #pragma unroll
    for (int t = 0; t < 4; ++t) acc[t] = (f32x4){0.f, 0.f, 0.f, 0.f};

    #pragma unroll
    for (int ks = 0; ks < 5; ++ks) {
        int k0 = ks * 32;
        bf16x8 a = *(const bf16x8*)&shH[(tn0 + c16) * HROW + k0 + ko];
        #pragma unroll
        for (int tt = 0; tt < 4; ++tt) {
            int t = h * 4 + tt;
            bf16x8 b = *(const bf16x8*)&W2T[(t * 16 + c16) * KPAD + k0 + ko];
            acc[tt] = __builtin_amdgcn_mfma_f32_16x16x32_bf16(a, b, acc[tt], 0, 0, 0);
        }
    }

    const int rbase = blk_n0 + tn0 + quad * 4;
    #pragma unroll
    for (int tt = 0; tt < 4; ++tt) {
        int cc = (h * 4 + tt) * 16 + c16;
        float badd = (h == 0) ? b2[cc] : 0.0f;
        #pragma unroll
        for (int i = 0; i < 4; ++i) {
            int node = rbase + i;
            if (node < N_NODES) ob[(size_t)node * 128 + cc] = f2bf(acc[tt][i] + badd);
        }
    }
}

// ---------------- layer-2 pull: one 8-lane group per node, pipelined edge walk ----------
__global__ __launch_bounds__(256) void k_pull(const int2* __restrict__ rows,
                                              const int* __restrict__ csr_src,
                                              const unsigned short* __restrict__ ob,
                                              const float* __restrict__ invd,
                                              float* __restrict__ out) {
    int wid = blockIdx.x * 4 + (threadIdx.x >> 6);
    int lane = threadIdx.x & 63;
    int g = lane >> 3;
    int t = lane & 7;
    int n = wid * 8 + g;
    if (n >= N_NODES) return;
    int2 re = rows[n];

    float acc[8];
    #pragma unroll
    for (int q = 0; q < 8; ++q) acc[q] = 0.0f;

    #pragma unroll 4
    for (int i = re.x; i < re.y; ++i) {
        int s = csr_src[i];
        bf16x8 v = *(const bf16x8*)&ob[(size_t)s * 128 + 64 + t * 8];
        #pragma unroll
        for (int q = 0; q < 8; ++q) acc[q] += bf2f((unsigned short)v[q]);
    }

    float id = invd[n];
    bf16x8 sv = *(const bf16x8*)&ob[(size_t)n * 128 + t * 8];
    f32x4 o0, o1;
    o0[0] = bf2f((unsigned short)sv[0]) + acc[0] * id;
    o0[1] = bf2f((unsigned short)sv[1]) + acc[1] * id;
    o0[2] = bf2f((unsigned short)sv[2]) + acc[2] * id;
    o0[3] = bf2f((unsigned short)sv[3]) + acc[3] * id;
    o1[0] = bf2f((unsigned short)sv[4]) + acc[4] * id;
    o1[1] = bf2f((unsigned short)sv[5]) + acc[5] * id;
    o1[2] = bf2f((unsigned short)sv[6]) + acc[6] * id;
    o1[3] = bf2f((unsigned short)sv[7]) + acc[7] * id;
    *(f32x4*)&out[(size_t)n * OUTF + t * 8]     = o0;
    *(f32x4*)&out[(size_t)n * OUTF + t * 8 + 4] = o1;
}

// ---------------- launcher ----------------

static inline size_t al256(size_t v) { return (v + 255) & ~(size_t)255; }

extern "C" void kernel_launch(void* const* d_in, const int* in_sizes, int n_in,
                              void* d_out, int out_size, void* d_ws, size_t ws_size,
                              hipStream_t stream) {
    const float* x   = (const float*)d_in[0];
    const int*   src = (const int*)d_in[1];
    const int*   dst = (const int*)d_in[2];
    const float* W1s = (const float*)d_in[3];
    const float* W1n = (const float*)d_in[4];
    const float* b1  = (const float*)d_in[5];
    const float* W2s = (const float*)d_in[6];
    const float* W2n = (const float*)d_in[7];
    const float* b2  = (const float*)d_in[8];
    float* out = (float*)d_out;

    char* ws = (char*)d_ws;
    size_t off = 0;
    int2*  rows      = (int2*)(ws + off); off += al256((size_t)N_NODES * 8);
    int*   csr_src   = (int*)(ws + off); off += al256((size_t)NBUK * CAP * 4);
    float* invd      = (float*)(ws + off); off += al256((size_t)N_NODES * 4);
    unsigned short* ob = (unsigned short*)(ws + off); off += al256((size_t)N_NODES * 128 * 2);
    float4* x4       = (float4*)(ws + off); off += al256((size_t)N_NODES * 16);
    unsigned int* pairbuf = (unsigned int*)(ws + off); off += al256((size_t)NBUK * CAP * 4);
    int*   bukcnt    = (int*)(ws + off); off += al256((size_t)NBUK * 4);
    unsigned short* W1B = (unsigned short*)(ws + off); off += al256((size_t)W1B_N * 2);
    unsigned short* W2T = (unsigned short*)(ws + off); off += al256((size_t)W2T_N * 2);

    // 1. zero bukcnt (tiny)
    k_init0<<<1, 256, 0, stream>>>(bukcnt);
    // 2. partition (+ distributed weight packing + x4 pad)
    k_part<<<NTILE, 256, 0, stream>>>(x, x4, src, dst, bukcnt, pairbuf,
                                      W1s, W1n, b1, W2s, W2n, W1B, W2T);
    // 3. per-bucket CSR finish
    k_fine<<<NBUK, 512, 0, stream>>>(bukcnt, pairbuf, rows, invd, csr_src);
    // 4. fused agg1 + layer1(MFMA) + layer2(MFMA), 2 waves/tile
    {
        int blocks = N_PAD / 32;                 // 3126
        k_gemm<<<blocks, 256, 0, stream>>>(x4, rows, csr_src, invd, W1B, W2T, b2, ob);
    }
    // 5. layer-2 pull
    {
        int blocks = (N_NODES + 31) / 32;
        k_pull<<<blocks, 256, 0, stream>>>(rows, csr_src, ob, invd, out);
    }
}